// Round 9
// baseline (210.928 us; speedup 1.0000x reference)
//
#include <hip/hip_runtime.h>

#define NTA 65536
#define NC 1024
#define NO 256
#define HDIM 332
#define HP 352          // H padded to multiple of 32
#define NSP 4
#define NOUT (NTA + NC + NTA*3)   // 263168 f32: en[NTA], E[NC], forces[NTA*3]
#define SORT_CAP (NTA + 256)      // 65792

// dpB geometry (overlay): 64 rows x 672B (bf16 [64][336]), +128B zeroed pad
#define DP_STRIDE 672
#define DP_BYTES  (64*DP_STRIDE)        // 43008
#define DP_PAD    128
#define LDS_MAIN  (2048 + DP_BYTES + DP_PAD)   // 45184; featB (2048+32768) fits under

typedef __attribute__((ext_vector_type(8))) short short8;
typedef __attribute__((ext_vector_type(4))) float f32x4;

// ---- workspace offsets (bytes) ----
#define OFF_CNT   0
#define OFF_CUR   64
#define OFF_START 128        // 8 ints
#define OFF_FLAG  160        // 1 uint: 1 = float inputs are bf16, 0 = f32
#define OFF_SORT  256        // int[65792] -> ends 263424
#define OFF_B1P   263680     // f32[4*352] -> 269312
#define OFF_W2P   269312     // f32[4*352] -> 274944
#define OFF_W1T   274944     // bf16 [4][352][256] -> 995840
#define OFF_W1P   995840     // bf16 [4][256][352] -> 1716736
#define OFF_FACC  1716736    // f32: forces[196608], Eatom[65536], Ecry[1024]

__device__ __forceinline__ unsigned short f2bf(float f){
  unsigned int u = __builtin_bit_cast(unsigned int, f);
  u += 0x7fffu + ((u>>16)&1u);
  return (unsigned short)(u>>16);
}
__device__ __forceinline__ float bf2f(unsigned short h){
  unsigned int u = ((unsigned int)h)<<16;
  return __builtin_bit_cast(float, u);
}
__device__ __forceinline__ float ldf(const void* p, int idx, int isbf){
  if (isbf) return bf2f(((const unsigned short*)p)[idx]);
  return ((const float*)p)[idx];
}

__global__ void k_init(float* __restrict__ acc, unsigned int* __restrict__ wshead,
                       int* __restrict__ sorted, const unsigned short* __restrict__ posu,
                       unsigned int* __restrict__ flag){
  int i = blockIdx.x*256 + threadIdx.x;   // grid 1028*256 = 263168 exactly
  acc[i] = 0.f;
  if (i < 32) wshead[i] = 0u;
  if (i < SORT_CAP) sorted[i] = -1;
  if (blockIdx.x == 1027 && threadIdx.x < 64){
    unsigned short u = posu[2*threadIdx.x];
    int e = (u>>7)&0xFF;
    bool inr = (e >= 110 && e <= 140);
    unsigned long long m = __ballot(inr);
    if (threadIdx.x == 0) flag[0] = (__popcll(m) >= 32) ? 1u : 0u;
  }
}

__global__ void k_count(const int* __restrict__ sym, unsigned int* __restrict__ cnt){
  __shared__ unsigned int h[NSP];
  int t = threadIdx.x;
  if (t < NSP) h[t] = 0u;
  __syncthreads();
  int i = blockIdx.x*256 + t;
  atomicAdd(&h[sym[i]], 1u);
  __syncthreads();
  if (t < NSP) atomicAdd(&cnt[t], h[t]);
}

__global__ void k_starts(const unsigned int* __restrict__ cnt, int* __restrict__ starts){
  if (threadIdx.x == 0){
    int a = 0; starts[0] = 0;
    for (int s=0;s<NSP;s++){ a += (int)(((cnt[s]+63u)>>6)<<6); starts[s+1] = a; }
  }
}

__global__ void k_scatter(const int* __restrict__ sym, const int* __restrict__ starts,
                          unsigned int* __restrict__ cur, int* __restrict__ sorted){
  int i = blockIdx.x*256 + threadIdx.x;
  int s = sym[i];
  int lane = threadIdx.x & 63;
  #pragma unroll
  for (int ss=0; ss<NSP; ss++){
    unsigned long long m = __ballot(s==ss);
    if (s == ss){
      int leader = __builtin_ctzll(m);
      int cw = __popcll(m);
      unsigned int b = 0;
      if (lane == leader) b = atomicAdd(&cur[ss], (unsigned int)cw);
      b = (unsigned int)__shfl((int)b, leader);
      int rank = __popcll(m & ((1ull<<lane) - 1ull));
      sorted[starts[ss] + (int)b + rank] = i;
    }
  }
}

__global__ void k_prepw(const void* __restrict__ W1, const void* __restrict__ b1,
                        const void* __restrict__ W2, const unsigned int* __restrict__ flag,
                        unsigned short* __restrict__ w1t, unsigned short* __restrict__ w1p,
                        float* __restrict__ b1p, float* __restrict__ w2p){
  const int isbf = (int)flag[0];
  int idx = blockIdx.x*256 + threadIdx.x;   // covers 4*352*256 exactly
  int s = idx / (HP*NO);
  int r = idx % (HP*NO);
  int j = r / NO;
  int i = r % NO;
  float v = (j < HDIM) ? ldf(W1, (s*NO + i)*HDIM + j, isbf) : 0.f;
  unsigned short hv = f2bf(v);
  w1t[(s*HP + j)*NO + i] = hv;
  w1p[(s*NO + i)*HP + j] = hv;
  if (i == 0){
    b1p[s*HP + j] = (j < HDIM) ? ldf(b1, s*HDIM + j, isbf) : 0.f;
    w2p[s*HP + j] = (j < HDIM) ? ldf(W2, s*HDIM + j, isbf) : 0.f;
  }
}

// Fused per-tile kernel v2. Tile = 64 atoms of one species. 4 waves, M-split.
// GEMM1': pre^T[352][64] = W1T[352][256] x feat^T   (K=256, 8 k-steps)
// GEMM2': dfeat^T[256][64] = W1p[256][352] x dpre^T (K=352, 11 k-steps)
// v2 changes (r8 counters: Occ 19.5%, MfmaUtil 7% -> latency-bound, LDS-capped):
//  - dpB OVERLAYS featB (epilogue2 recomputes tanh instead of re-reading featB)
//  - dpB stride 720->672 (XOR swz keeps b128 reads ~2-way: banks of first dword
//    for c=0..7 = {0,12,24,4,16,28,8,20} -> all 32 banks covered)
//  - LDS 80896 -> 45184 B  => 3 blocks/CU (was 2)
//  - j>=336 dpre writes skipped (would cross row stride; those K-taps have A=0)
//  - 128B read-overrun pad zeroed (avoid NaN*0 in MFMA)
__global__ __launch_bounds__(256,3) void k_main(
    const int* __restrict__ sorted, const int* __restrict__ starts,
    const void* __restrict__ pos, const void* __restrict__ Wd,
    const unsigned short* __restrict__ W1T, const unsigned short* __restrict__ W1P,
    const float* __restrict__ b1p, const float* __restrict__ w2p,
    const void* __restrict__ b2g, const unsigned int* __restrict__ flag,
    float* __restrict__ Eatom, float* __restrict__ forces)
{
  extern __shared__ char smem[];
  ushort4* wdT = (ushort4*)smem;        // [256] {wx,wy,wz,0} = 2048 B
  char* featB = smem + 2048;            // bf16 [64][256], XOR-swz rows of 512B
  char* dpB   = smem + 2048;            // OVERLAY: bf16 rows of 672B + 128B pad

  const int base = blockIdx.x*64;
  if (base >= starts[4]) return;
  const int isbf = (int)flag[0];
  int sp = 0;
  #pragma unroll
  for (int s=1;s<NSP;s++) sp = (base >= starts[s]) ? s : sp;

  const int tid = threadIdx.x;
  const int l = tid & 63;
  const int w = tid >> 6;
  const int c = l & 15;
  const int g = l >> 4;

  {
    float x = ldf(Wd, tid, isbf), y = ldf(Wd, NO+tid, isbf), z = ldf(Wd, 2*NO+tid, isbf);
    ushort4 u; u.x = f2bf(x); u.y = f2bf(y); u.z = f2bf(z); u.w = 0;
    wdT[tid] = u;
  }
  if (tid < DP_PAD/4) *(unsigned int*)(dpB + DP_BYTES + tid*4) = 0u;  // zero pad

  // per-lane column atoms (columns m = nb*16+c): positions for epilogue2 recompute
  int a4[4]; float px4[4], py4[4], pz4[4];
  #pragma unroll
  for (int nb=0;nb<4;nb++){
    int aa = sorted[base + nb*16 + c];
    a4[nb] = aa;
    float x=0.f,y=0.f,z=0.f;
    if (aa >= 0){ x=ldf(pos,3*aa,isbf); y=ldf(pos,3*aa+1,isbf); z=ldf(pos,3*aa+2,isbf); }
    px4[nb]=x; py4[nb]=y; pz4[nb]=z;
  }
  __syncthreads();

  // ---- stage feat tile: thread handles row m=l, 64-col chunk w ----
  {
    const int m = l;
    int a = sorted[base + m];
    float px=0.f, py=0.f, pz=0.f;
    if (a >= 0){ px = ldf(pos,3*a,isbf); py = ldf(pos,3*a+1,isbf); pz = ldf(pos,3*a+2,isbf); }
    const int swz = (m&7)<<4;
    char* rowp = featB + m*512;
    #pragma unroll
    for (int k8=0;k8<8;k8++){
      int i0 = w*64 + k8*8;
      unsigned int pk[4];
      #pragma unroll
      for (int p2=0;p2<4;p2++){
        unsigned short hv[2];
        #pragma unroll
        for (int e2=0;e2<2;e2++){
          ushort4 wv = wdT[i0 + 2*p2 + e2];
          float v = px*bf2f(wv.x) + py*bf2f(wv.y) + pz*bf2f(wv.z);
          float e = __expf(2.f*v);
          hv[e2] = f2bf(1.f - 2.f/(e+1.f));   // tanh
        }
        pk[p2] = (unsigned int)hv[0] | ((unsigned int)hv[1]<<16);
      }
      *(uint4*)(rowp + ((i0*2) ^ swz)) = make_uint4(pk[0],pk[1],pk[2],pk[3]);
    }
  }
  __syncthreads();

  // ---- GEMM1' ----
  const unsigned short* W1Ts = W1T + sp*HP*NO;
  f32x4 acc[6][4];
  #pragma unroll
  for (int t=0;t<6;t++)
    #pragma unroll
    for (int nb=0;nb<4;nb++) acc[t][nb] = f32x4{0.f,0.f,0.f,0.f};
  const int nT1 = (w==3) ? 4 : 6;   // 22 j-frags: 6+6+6+4

  #pragma unroll
  for (int kk=0; kk<8; kk++){
    short8 bfr[4];
    #pragma unroll
    for (int nb=0;nb<4;nb++){
      int m = nb*16 + c;
      bfr[nb] = *(const short8*)(featB + m*512 + ((kk*64 + g*16) ^ ((m&7)<<4)));
    }
    #pragma unroll
    for (int t=0;t<6;t++){
      if (t < nT1){
        const short8 afr = *(const short8*)((const char*)W1Ts + ((6*w+t)*16 + c)*512 + kk*64 + g*16);
        #pragma unroll
        for (int nb=0;nb<4;nb++)
          acc[t][nb] = __builtin_amdgcn_mfma_f32_16x16x32_bf16(afr, bfr[nb], acc[t][nb], 0,0,0);
      }
    }
  }
  __syncthreads();   // all waves done reading featB (dpB overlays it)

  // ---- epilogue 1: bias, silu, per-atom energy partials, dpre -> dpB ----
  const float* b1s = b1p + sp*HP;
  const float* w2s = w2p + sp*HP;
  float b2v = (w==0) ? ldf(b2g, sp, isbf) : 0.f;
  float esp[4] = {0.f,0.f,0.f,0.f};
  #pragma unroll
  for (int t=0;t<6;t++){
    if (t < nT1){
      const int j0 = (6*w+t)*16 + g*4;
      const float4 b1v = *(const float4*)(b1s + j0);
      const float4 w2v = *(const float4*)(w2s + j0);
      const float* b1a = (const float*)&b1v;
      const float* w2a = (const float*)&w2v;
      #pragma unroll
      for (int nb=0;nb<4;nb++){
        const int m = nb*16 + c;
        unsigned short dph[4];
        #pragma unroll
        for (int q=0;q<4;q++){
          float pre = acc[t][nb][q] + b1a[q];
          float sg = 1.f/(1.f + __expf(-pre));
          float h = pre*sg;
          esp[nb] += h*w2a[q];
          float dsl = sg*(1.f + pre*(1.f - sg));   // silu'
          dph[q] = f2bf(w2a[q]*dsl);               // dpre
        }
        if (j0 < 336)  // j>=336: beyond row stride; A is zero there anyway
          *(uint2*)(dpB + m*DP_STRIDE + ((j0*2) ^ ((m&7)<<4))) =
              make_uint2((unsigned)dph[0] | ((unsigned)dph[1]<<16),
                         (unsigned)dph[2] | ((unsigned)dph[3]<<16));
      }
    }
  }
  #pragma unroll
  for (int nb=0;nb<4;nb++){
    float e = esp[nb];
    e += __shfl_xor(e, 16);
    e += __shfl_xor(e, 32);
    if (g == 0 && a4[nb] >= 0) atomicAdd(&Eatom[a4[nb]], e + b2v);
  }
  __syncthreads();   // dpB complete

  // ---- GEMM2' ----
  const unsigned short* W1Ps = W1P + sp*NO*HP;
  f32x4 acc2[4][4];
  #pragma unroll
  for (int t2=0;t2<4;t2++)
    #pragma unroll
    for (int nb=0;nb<4;nb++) acc2[t2][nb] = f32x4{0.f,0.f,0.f,0.f};

  #pragma unroll
  for (int kk=0; kk<11; kk++){
    short8 bfr[4];
    #pragma unroll
    for (int nb=0;nb<4;nb++){
      int m = nb*16 + c;
      bfr[nb] = *(const short8*)(dpB + m*DP_STRIDE + ((kk*64 + g*16) ^ ((m&7)<<4)));
    }
    #pragma unroll
    for (int t2=0;t2<4;t2++){
      const short8 afr = *(const short8*)((const char*)W1Ps + ((4*w+t2)*16 + c)*704 + kk*64 + g*16);
      #pragma unroll
      for (int nb=0;nb<4;nb++)
        acc2[t2][nb] = __builtin_amdgcn_mfma_f32_16x16x32_bf16(afr, bfr[nb], acc2[t2][nb], 0,0,0);
    }
  }

  // ---- epilogue 2: f = tanh recomputed; dpos = (dfeat*(1-f^2)) @ Wd^T ----
  float fax[4] = {0.f,0.f,0.f,0.f};
  float fay[4] = {0.f,0.f,0.f,0.f};
  float faz[4] = {0.f,0.f,0.f,0.f};
  #pragma unroll
  for (int t2=0;t2<4;t2++){
    const int i0 = (4*w+t2)*16 + g*4;
    #pragma unroll
    for (int q=0;q<4;q++){
      ushort4 wv = wdT[i0 + q];
      float wx = bf2f(wv.x), wy = bf2f(wv.y), wz = bf2f(wv.z);
      #pragma unroll
      for (int nb=0;nb<4;nb++){
        float v = px4[nb]*wx + py4[nb]*wy + pz4[nb]*wz;
        float e = __expf(2.f*v);
        float f = 1.f - 2.f/(e+1.f);
        float gsc = acc2[t2][nb][q] * (1.f - f*f);
        fax[nb] += gsc*wx;
        fay[nb] += gsc*wy;
        faz[nb] += gsc*wz;
      }
    }
  }
  #pragma unroll
  for (int nb=0;nb<4;nb++){
    float x = fax[nb], y = fay[nb], z = faz[nb];
    x += __shfl_xor(x, 16); x += __shfl_xor(x, 32);
    y += __shfl_xor(y, 16); y += __shfl_xor(y, 32);
    z += __shfl_xor(z, 16); z += __shfl_xor(z, 32);
    if (g == 0 && a4[nb] >= 0){
      int a = a4[nb];
      atomicAdd(&forces[3*a+0], x);
      atomicAdd(&forces[3*a+1], y);
      atomicAdd(&forces[3*a+2], z);
    }
  }
}

__global__ void k_seg(const float* __restrict__ Eatom, const int* __restrict__ crys,
                      float* __restrict__ Ecry){
  int i = blockIdx.x*256 + threadIdx.x;   // 256 blocks -> 65536 threads
  atomicAdd(&Ecry[crys[i]], Eatom[i]);
}

// Output: f32, reference order (energies=en[NTA], energy=E[NC], forces[NTA,3])
__global__ void k_out(const float* __restrict__ Eatom, const float* __restrict__ Ecry,
                      const float* __restrict__ Facc, float* __restrict__ out){
  int i = blockIdx.x*256 + threadIdx.x;   // grid covers 263168 exactly
  float v;
  if (i < NTA)            v = Eatom[i];
  else if (i < NTA + NC)  v = Ecry[i - NTA];
  else                    v = Facc[i - NTA - NC];
  out[i] = v;
}

extern "C" void kernel_launch(void* const* d_in, const int* in_sizes, int n_in,
                              void* d_out, int out_size, void* d_ws, size_t ws_size,
                              hipStream_t stream) {
  const int*   symbols    = (const int*)  d_in[0];
  const void*  positions  = d_in[1];
  // d_in[2] cells, d_in[3] pbcs, d_in[4] energyidx: unused by the math
  const int*   crystalidx = (const int*)  d_in[5];
  const void*  Wd         = d_in[6];
  const void*  W1         = d_in[7];
  const void*  b1         = d_in[8];
  const void*  W2         = d_in[9];
  const void*  b2         = d_in[10];
  float* dout = (float*)d_out;   // f32 output buffer

  char* ws = (char*)d_ws;
  unsigned int* cnt    = (unsigned int*)(ws + OFF_CNT);
  unsigned int* cur    = (unsigned int*)(ws + OFF_CUR);
  int*          starts = (int*)         (ws + OFF_START);
  unsigned int* flag   = (unsigned int*)(ws + OFF_FLAG);
  int*          sorted = (int*)         (ws + OFF_SORT);
  float*        b1p    = (float*)       (ws + OFF_B1P);
  float*        w2p    = (float*)       (ws + OFF_W2P);
  unsigned short* w1t  = (unsigned short*)(ws + OFF_W1T);
  unsigned short* w1pp = (unsigned short*)(ws + OFF_W1P);
  float*        Facc   = (float*)       (ws + OFF_FACC);   // forces[196608]
  float*        Eatom  = Facc + NTA*3;                     // [65536]
  float*        Ecry   = Eatom + NTA;                      // [1024]

  hipFuncSetAttribute((const void*)k_main,
                      hipFuncAttributeMaxDynamicSharedMemorySize, LDS_MAIN);

  k_init   <<<1028,256, 0, stream>>>(Facc, (unsigned int*)ws, sorted,
                                     (const unsigned short*)positions, flag);
  k_count  <<<256, 256, 0, stream>>>(symbols, cnt);
  k_starts <<<1,    64, 0, stream>>>(cnt, starts);
  k_scatter<<<256, 256, 0, stream>>>(symbols, starts, cur, sorted);
  k_prepw  <<<1408,256, 0, stream>>>(W1, b1, W2, flag, w1t, w1pp, b1p, w2p);
  k_main   <<<1028,256, LDS_MAIN, stream>>>(sorted, starts, positions, Wd,
                                            w1t, w1pp, b1p, w2p, b2, flag,
                                            Eatom, Facc);
  k_seg    <<<256, 256, 0, stream>>>(Eatom, crystalidx, Ecry);
  k_out    <<<1028,256, 0, stream>>>(Eatom, Ecry, Facc, dout);
}

// Round 10
// 174.824 us; speedup vs baseline: 1.2065x; 1.2065x over previous
//
#include <hip/hip_runtime.h>

#define NTA 65536
#define NC 1024
#define NO 256
#define HDIM 332
#define HP 352          // H padded to multiple of 32
#define NSP 4
#define NOUT (NTA + NC + NTA*3)   // 263168 f32: en[NTA], E[NC], forces[NTA*3]
#define SORT_CAP (NTA + 256)      // 65792

// LDS map for k_main (dynamic, 81920 B = exactly 2 blocks/CU):
//   [0,2048)          wdT        [256] ushort4
//   [2048,34816)      featB      bf16 [64] rows x 512B, XOR-swizzled
//   [34816,80896)     dpB        bf16 [64] rows x 720B   (no swizzle; 720 spreads banks)
//                     Fpart      (overlays dpB after GEMM2) [4][64][3] f32
//   [80896,81920)     Epart      [4][64] f32
#define LDS_MAIN 81920

typedef __attribute__((ext_vector_type(8))) short short8;
typedef __attribute__((ext_vector_type(4))) float f32x4;

// ---- workspace offsets (bytes) ----
#define OFF_CNT   0
#define OFF_CUR   64
#define OFF_START 128        // 8 ints
#define OFF_FLAG  160        // 1 uint: 1 = float inputs are bf16, 0 = f32
#define OFF_SORT  256        // int[65792] -> ends 263424
#define OFF_B1P   263680     // f32[4*352] -> 269312
#define OFF_W2P   269312     // f32[4*352] -> 274944
#define OFF_W1T   274944     // bf16 [4][352][256] -> 995840
#define OFF_W1P   995840     // bf16 [4][256][352] -> 1716736
#define OFF_FACC  1716736    // f32: forces[196608], Eatom[65536], Ecry[1024]

__device__ __forceinline__ unsigned short f2bf(float f){
  unsigned int u = __builtin_bit_cast(unsigned int, f);
  u += 0x7fffu + ((u>>16)&1u);
  return (unsigned short)(u>>16);
}
__device__ __forceinline__ float bf2f(unsigned short h){
  unsigned int u = ((unsigned int)h)<<16;
  return __builtin_bit_cast(float, u);
}
__device__ __forceinline__ float ldf(const void* p, int idx, int isbf){
  if (isbf) return bf2f(((const unsigned short*)p)[idx]);
  return ((const float*)p)[idx];
}
__device__ __forceinline__ float rcpf(float x){ return __builtin_amdgcn_rcpf(x); }

__global__ void k_init(float* __restrict__ acc, unsigned int* __restrict__ wshead,
                       int* __restrict__ sorted, const unsigned short* __restrict__ posu,
                       unsigned int* __restrict__ flag){
  int i = blockIdx.x*256 + threadIdx.x;   // grid 1028*256 = 263168 exactly
  acc[i] = 0.f;
  if (i < 32) wshead[i] = 0u;
  if (i < SORT_CAP) sorted[i] = -1;
  if (blockIdx.x == 1027 && threadIdx.x < 64){
    unsigned short u = posu[2*threadIdx.x];
    int e = (u>>7)&0xFF;
    bool inr = (e >= 110 && e <= 140);
    unsigned long long m = __ballot(inr);
    if (threadIdx.x == 0) flag[0] = (__popcll(m) >= 32) ? 1u : 0u;
  }
}

__global__ void k_count(const int* __restrict__ sym, unsigned int* __restrict__ cnt){
  __shared__ unsigned int h[NSP];
  int t = threadIdx.x;
  if (t < NSP) h[t] = 0u;
  __syncthreads();
  int i = blockIdx.x*256 + t;
  atomicAdd(&h[sym[i]], 1u);
  __syncthreads();
  if (t < NSP) atomicAdd(&cnt[t], h[t]);
}

__global__ void k_starts(const unsigned int* __restrict__ cnt, int* __restrict__ starts){
  if (threadIdx.x == 0){
    int a = 0; starts[0] = 0;
    for (int s=0;s<NSP;s++){ a += (int)(((cnt[s]+63u)>>6)<<6); starts[s+1] = a; }
  }
}

__global__ void k_scatter(const int* __restrict__ sym, const int* __restrict__ starts,
                          unsigned int* __restrict__ cur, int* __restrict__ sorted){
  int i = blockIdx.x*256 + threadIdx.x;
  int s = sym[i];
  int lane = threadIdx.x & 63;
  #pragma unroll
  for (int ss=0; ss<NSP; ss++){
    unsigned long long m = __ballot(s==ss);
    if (s == ss){
      int leader = __builtin_ctzll(m);
      int cw = __popcll(m);
      unsigned int b = 0;
      if (lane == leader) b = atomicAdd(&cur[ss], (unsigned int)cw);
      b = (unsigned int)__shfl((int)b, leader);
      int rank = __popcll(m & ((1ull<<lane) - 1ull));
      sorted[starts[ss] + (int)b + rank] = i;
    }
  }
}

__global__ void k_prepw(const void* __restrict__ W1, const void* __restrict__ b1,
                        const void* __restrict__ W2, const unsigned int* __restrict__ flag,
                        unsigned short* __restrict__ w1t, unsigned short* __restrict__ w1p,
                        float* __restrict__ b1p, float* __restrict__ w2p){
  const int isbf = (int)flag[0];
  int idx = blockIdx.x*256 + threadIdx.x;   // covers 4*352*256 exactly
  int s = idx / (HP*NO);
  int r = idx % (HP*NO);
  int j = r / NO;
  int i = r % NO;
  float v = (j < HDIM) ? ldf(W1, (s*NO + i)*HDIM + j, isbf) : 0.f;
  unsigned short hv = f2bf(v);
  w1t[(s*HP + j)*NO + i] = hv;
  w1p[(s*NO + i)*HP + j] = hv;
  if (i == 0){
    b1p[s*HP + j] = (j < HDIM) ? ldf(b1, s*HDIM + j, isbf) : 0.f;
    w2p[s*HP + j] = (j < HDIM) ? ldf(W2, s*HDIM + j, isbf) : 0.f;
  }
}

// Fused per-tile kernel v3 (= r8-correct v1 + no-atomics + rcp + kk unroll).
// Tile = 64 atoms of one species; atoms UNIQUE per tile (sorted, disjoint) ->
// E/forces reduce block-locally in LDS, plain f32 stores (no device atomics).
// GEMM1': pre^T[352][64] = W1T[352][256] x feat^T   (K=256, 8 k-steps)
// GEMM2': dfeat^T[256][64] = W1p[256][352] x dpre^T (K=352, 11 k-steps)
// MFMA C/D layout (HW-verified r3 probe): reg q of lane l -> row=(l>>4)*4+q, col=l&15.
__global__ __launch_bounds__(256,2) void k_main(
    const int* __restrict__ sorted, const int* __restrict__ starts,
    const void* __restrict__ pos, const void* __restrict__ Wd,
    const unsigned short* __restrict__ W1T, const unsigned short* __restrict__ W1P,
    const float* __restrict__ b1p, const float* __restrict__ w2p,
    const void* __restrict__ b2g, const unsigned int* __restrict__ flag,
    float* __restrict__ Eatom, float* __restrict__ forces)
{
  extern __shared__ char smem[];
  ushort4* wdT = (ushort4*)smem;            // [256] {wx,wy,wz,0}
  char* featB  = smem + 2048;               // bf16 [64][256], XOR-swz rows of 512B
  char* dpB    = smem + 34816;              // bf16 [64] rows x 720B
  float* Fpart = (float*)(smem + 34816);    // overlays dpB after GEMM2: [4][64][3]
  float* Epart = (float*)(smem + 80896);    // [4][64]

  const int base = blockIdx.x*64;
  if (base >= starts[4]) return;
  const int isbf = (int)flag[0];
  int sp = 0;
  #pragma unroll
  for (int s=1;s<NSP;s++) sp = (base >= starts[s]) ? s : sp;

  const int tid = threadIdx.x;
  const int l = tid & 63;
  const int w = tid >> 6;
  const int c = l & 15;
  const int g = l >> 4;

  {
    float x = ldf(Wd, tid, isbf), y = ldf(Wd, NO+tid, isbf), z = ldf(Wd, 2*NO+tid, isbf);
    ushort4 u; u.x = f2bf(x); u.y = f2bf(y); u.z = f2bf(z); u.w = 0;
    wdT[tid] = u;
  }
  __syncthreads();

  // ---- stage feat tile: thread handles row m=l, 64-col chunk w ----
  {
    const int m = l;
    int a = sorted[base + m];
    float px=0.f, py=0.f, pz=0.f;
    if (a >= 0){ px = ldf(pos,3*a,isbf); py = ldf(pos,3*a+1,isbf); pz = ldf(pos,3*a+2,isbf); }
    const int swz = (m&7)<<4;
    char* rowp = featB + m*512;
    #pragma unroll
    for (int k8=0;k8<8;k8++){
      int i0 = w*64 + k8*8;
      unsigned int pk[4];
      #pragma unroll
      for (int p2=0;p2<4;p2++){
        unsigned short hv[2];
        #pragma unroll
        for (int e2=0;e2<2;e2++){
          ushort4 wv = wdT[i0 + 2*p2 + e2];
          float v = px*bf2f(wv.x) + py*bf2f(wv.y) + pz*bf2f(wv.z);
          float e = __expf(2.f*v);
          hv[e2] = f2bf(1.f - 2.f*rcpf(e+1.f));   // tanh via rcp (no IEEE div)
        }
        pk[p2] = (unsigned int)hv[0] | ((unsigned int)hv[1]<<16);
      }
      *(uint4*)(rowp + ((i0*2) ^ swz)) = make_uint4(pk[0],pk[1],pk[2],pk[3]);
    }
  }
  __syncthreads();

  // ---- GEMM1' ----
  const unsigned short* W1Ts = W1T + sp*HP*NO;
  f32x4 acc[6][4];
  #pragma unroll
  for (int t=0;t<6;t++)
    #pragma unroll
    for (int nb=0;nb<4;nb++) acc[t][nb] = f32x4{0.f,0.f,0.f,0.f};
  const int nT1 = (w==3) ? 4 : 6;   // 22 j-frags: 6+6+6+4

  #pragma unroll
  for (int kk=0; kk<8; kk++){
    short8 bfr[4];
    #pragma unroll
    for (int nb=0;nb<4;nb++){
      int m = nb*16 + c;
      bfr[nb] = *(const short8*)(featB + m*512 + ((kk*64 + g*16) ^ ((m&7)<<4)));
    }
    #pragma unroll
    for (int t=0;t<6;t++){
      if (t < nT1){
        const short8 afr = *(const short8*)((const char*)W1Ts + ((6*w+t)*16 + c)*512 + kk*64 + g*16);
        #pragma unroll
        for (int nb=0;nb<4;nb++)
          acc[t][nb] = __builtin_amdgcn_mfma_f32_16x16x32_bf16(afr, bfr[nb], acc[t][nb], 0,0,0);
      }
    }
  }

  // ---- epilogue 1: bias, silu, E partials -> LDS, dpre -> dpB ----
  const float* b1s = b1p + sp*HP;
  const float* w2s = w2p + sp*HP;
  float esp[4] = {0.f,0.f,0.f,0.f};
  #pragma unroll
  for (int t=0;t<6;t++){
    if (t < nT1){
      const int j0 = (6*w+t)*16 + g*4;
      const float4 b1v = *(const float4*)(b1s + j0);
      const float4 w2v = *(const float4*)(w2s + j0);
      const float* b1a = (const float*)&b1v;
      const float* w2a = (const float*)&w2v;
      #pragma unroll
      for (int nb=0;nb<4;nb++){
        const int m = nb*16 + c;
        unsigned short dph[4];
        #pragma unroll
        for (int q=0;q<4;q++){
          float pre = acc[t][nb][q] + b1a[q];
          float sg = rcpf(1.f + __expf(-pre));     // sigmoid via rcp
          float h = pre*sg;
          esp[nb] += h*w2a[q];
          float dsl = sg*(1.f + pre*(1.f - sg));   // silu'
          dph[q] = f2bf(w2a[q]*dsl);               // dpre
        }
        *(uint2*)(dpB + m*720 + j0*2) =
            make_uint2((unsigned)dph[0] | ((unsigned)dph[1]<<16),
                       (unsigned)dph[2] | ((unsigned)dph[3]<<16));
      }
    }
  }
  #pragma unroll
  for (int nb=0;nb<4;nb++){
    float e = esp[nb];
    e += __shfl_xor(e, 16);
    e += __shfl_xor(e, 32);
    if (g == 0) Epart[w*64 + nb*16 + c] = e;   // block-local partial (no atomic)
  }
  __syncthreads();   // dpB + Epart complete

  // ---- GEMM2' ----
  const unsigned short* W1Ps = W1P + sp*NO*HP;
  f32x4 acc2[4][4];
  #pragma unroll
  for (int t2=0;t2<4;t2++)
    #pragma unroll
    for (int nb=0;nb<4;nb++) acc2[t2][nb] = f32x4{0.f,0.f,0.f,0.f};

  #pragma unroll
  for (int kk=0; kk<11; kk++){
    short8 bfr[4];
    #pragma unroll
    for (int nb=0;nb<4;nb++){
      int m = nb*16 + c;
      bfr[nb] = *(const short8*)(dpB + m*720 + kk*64 + g*16);
    }
    #pragma unroll
    for (int t2=0;t2<4;t2++){
      const short8 afr = *(const short8*)((const char*)W1Ps + ((4*w+t2)*16 + c)*704 + kk*64 + g*16);
      #pragma unroll
      for (int nb=0;nb<4;nb++)
        acc2[t2][nb] = __builtin_amdgcn_mfma_f32_16x16x32_bf16(afr, bfr[nb], acc2[t2][nb], 0,0,0);
    }
  }

  // ---- epilogue 2: dpos = (dfeat * (1-feat^2)) @ Wd^T ----
  float fax[4] = {0.f,0.f,0.f,0.f};
  float fay[4] = {0.f,0.f,0.f,0.f};
  float faz[4] = {0.f,0.f,0.f,0.f};
  #pragma unroll
  for (int t2=0;t2<4;t2++){
    const int i0 = (4*w+t2)*16 + g*4;
    #pragma unroll
    for (int nb=0;nb<4;nb++){
      const int m = nb*16 + c;
      uint2 fpk = *(const uint2*)(featB + m*512 + ((i0*2) ^ ((m&7)<<4)));
      unsigned short fh[4];
      fh[0] = (unsigned short)(fpk.x & 0xffffu); fh[1] = (unsigned short)(fpk.x >> 16);
      fh[2] = (unsigned short)(fpk.y & 0xffffu); fh[3] = (unsigned short)(fpk.y >> 16);
      #pragma unroll
      for (int q=0;q<4;q++){
        float ff = bf2f(fh[q]);
        float gsc = acc2[t2][nb][q] * (1.f - ff*ff);
        ushort4 wv = wdT[i0 + q];
        fax[nb] += gsc*bf2f(wv.x);
        fay[nb] += gsc*bf2f(wv.y);
        faz[nb] += gsc*bf2f(wv.z);
      }
    }
  }
  #pragma unroll
  for (int nb=0;nb<4;nb++){
    float x = fax[nb], y = fay[nb], z = faz[nb];
    x += __shfl_xor(x, 16); x += __shfl_xor(x, 32);
    y += __shfl_xor(y, 16); y += __shfl_xor(y, 32);
    z += __shfl_xor(z, 16); z += __shfl_xor(z, 32);
    fax[nb] = x; fay[nb] = y; faz[nb] = z;
  }
  __syncthreads();   // all waves done reading dpB -> safe to overlay Fpart
  #pragma unroll
  for (int nb=0;nb<4;nb++){
    if (g == 0){
      const int m = nb*16 + c;
      Fpart[w*192 + m*3 + 0] = fax[nb];
      Fpart[w*192 + m*3 + 1] = fay[nb];
      Fpart[w*192 + m*3 + 2] = faz[nb];
    }
  }
  __syncthreads();

  // ---- final: one wave sums 4 partials, plain stores (atoms unique per tile) ----
  if (w == 0){
    int a = sorted[base + l];
    if (a >= 0){
      float E = Epart[l] + Epart[64+l] + Epart[128+l] + Epart[192+l]
              + ldf(b2g, sp, isbf);
      Eatom[a] = E;
      float fx = 0.f, fy = 0.f, fz = 0.f;
      #pragma unroll
      for (int ww=0; ww<4; ww++){
        fx += Fpart[ww*192 + l*3 + 0];
        fy += Fpart[ww*192 + l*3 + 1];
        fz += Fpart[ww*192 + l*3 + 2];
      }
      forces[3*a+0] = fx;
      forces[3*a+1] = fy;
      forces[3*a+2] = fz;
    }
  }
}

__global__ void k_seg(const float* __restrict__ Eatom, const int* __restrict__ crys,
                      float* __restrict__ Ecry){
  int i = blockIdx.x*256 + threadIdx.x;   // 256 blocks -> 65536 threads
  atomicAdd(&Ecry[crys[i]], Eatom[i]);
}

// Output: f32, reference order (energies=en[NTA], energy=E[NC], forces[NTA,3])
__global__ void k_out(const float* __restrict__ Eatom, const float* __restrict__ Ecry,
                      const float* __restrict__ Facc, float* __restrict__ out){
  int i = blockIdx.x*256 + threadIdx.x;   // grid covers 263168 exactly
  float v;
  if (i < NTA)            v = Eatom[i];
  else if (i < NTA + NC)  v = Ecry[i - NTA];
  else                    v = Facc[i - NTA - NC];
  out[i] = v;
}

extern "C" void kernel_launch(void* const* d_in, const int* in_sizes, int n_in,
                              void* d_out, int out_size, void* d_ws, size_t ws_size,
                              hipStream_t stream) {
  const int*   symbols    = (const int*)  d_in[0];
  const void*  positions  = d_in[1];
  // d_in[2] cells, d_in[3] pbcs, d_in[4] energyidx: unused by the math
  const int*   crystalidx = (const int*)  d_in[5];
  const void*  Wd         = d_in[6];
  const void*  W1         = d_in[7];
  const void*  b1         = d_in[8];
  const void*  W2         = d_in[9];
  const void*  b2         = d_in[10];
  float* dout = (float*)d_out;   // f32 output buffer

  char* ws = (char*)d_ws;
  unsigned int* cnt    = (unsigned int*)(ws + OFF_CNT);
  unsigned int* cur    = (unsigned int*)(ws + OFF_CUR);
  int*          starts = (int*)         (ws + OFF_START);
  unsigned int* flag   = (unsigned int*)(ws + OFF_FLAG);
  int*          sorted = (int*)         (ws + OFF_SORT);
  float*        b1p    = (float*)       (ws + OFF_B1P);
  float*        w2p    = (float*)       (ws + OFF_W2P);
  unsigned short* w1t  = (unsigned short*)(ws + OFF_W1T);
  unsigned short* w1pp = (unsigned short*)(ws + OFF_W1P);
  float*        Facc   = (float*)       (ws + OFF_FACC);   // forces[196608]
  float*        Eatom  = Facc + NTA*3;                     // [65536]
  float*        Ecry   = Eatom + NTA;                      // [1024]

  hipFuncSetAttribute((const void*)k_main,
                      hipFuncAttributeMaxDynamicSharedMemorySize, LDS_MAIN);

  k_init   <<<1028,256, 0, stream>>>(Facc, (unsigned int*)ws, sorted,
                                     (const unsigned short*)positions, flag);
  k_count  <<<256, 256, 0, stream>>>(symbols, cnt);
  k_starts <<<1,    64, 0, stream>>>(cnt, starts);
  k_scatter<<<256, 256, 0, stream>>>(symbols, starts, cur, sorted);
  k_prepw  <<<1408,256, 0, stream>>>(W1, b1, W2, flag, w1t, w1pp, b1p, w2p);
  k_main   <<<1028,256, LDS_MAIN, stream>>>(sorted, starts, positions, Wd,
                                            w1t, w1pp, b1p, w2p, b2, flag,
                                            Eatom, Facc);
  k_seg    <<<256, 256, 0, stream>>>(Eatom, crystalidx, Ecry);
  k_out    <<<1028,256, 0, stream>>>(Eatom, Ecry, Facc, dout);
}

// Round 11
// 164.979 us; speedup vs baseline: 1.2785x; 1.0597x over previous
//
#include <hip/hip_runtime.h>

#define NTA 65536
#define NC 1024
#define NO 256
#define HDIM 332
#define HP 352          // H padded to multiple of 32
#define NSP 4
#define NOUT (NTA + NC + NTA*3)   // 263168 f32: en[NTA], E[NC], forces[NTA*3]
#define SORT_CAP (NTA + 256)      // 65792

// LDS map for k_main (dynamic, 49152 B -> 3 blocks/CU):
//   [0,2048)        wdT    [256] ushort4
//   [2048,34816)    featB  bf16 [64] rows x 512B, XOR-swz   (phases 1-2)
//   [2048,48128)    dpB    bf16 [64] rows x 720B, linear    (OVERLAY, phases 3-4)
//   [2048,5120)     Fpart  [4][64][3] f32                   (OVERLAY, phase 5)
//   [48128,49152)   Epart  [4][64] f32
#define DP_STRIDE 720
#define LDS_MAIN  49152

typedef __attribute__((ext_vector_type(8))) short short8;
typedef __attribute__((ext_vector_type(4))) float f32x4;

// ---- workspace offsets (bytes) ----
#define OFF_CNT   0
#define OFF_CUR   64
#define OFF_START 128        // 8 ints
#define OFF_FLAG  160        // 1 uint: 1 = float inputs are bf16, 0 = f32
#define OFF_SORT  256        // int[65792] -> ends 263424
#define OFF_B1P   263680     // f32[4*352] -> 269312
#define OFF_W2P   269312     // f32[4*352] -> 274944
#define OFF_W1T   274944     // bf16 [4][352][256] -> 995840
#define OFF_W1P   995840     // bf16 [4][256][352] -> 1716736
#define OFF_FACC  1716736    // f32: forces[196608], Eatom[65536], Ecry[1024]

__device__ __forceinline__ unsigned short f2bf(float f){
  unsigned int u = __builtin_bit_cast(unsigned int, f);
  u += 0x7fffu + ((u>>16)&1u);
  return (unsigned short)(u>>16);
}
__device__ __forceinline__ float bf2f(unsigned short h){
  unsigned int u = ((unsigned int)h)<<16;
  return __builtin_bit_cast(float, u);
}
__device__ __forceinline__ float ldf(const void* p, int idx, int isbf){
  if (isbf) return bf2f(((const unsigned short*)p)[idx]);
  return ((const float*)p)[idx];
}
__device__ __forceinline__ float rcpf(float x){ return __builtin_amdgcn_rcpf(x); }

__global__ void k_init(float* __restrict__ acc, unsigned int* __restrict__ wshead,
                       int* __restrict__ sorted, const unsigned short* __restrict__ posu,
                       unsigned int* __restrict__ flag){
  int i = blockIdx.x*256 + threadIdx.x;   // grid 1028*256 = 263168 exactly
  acc[i] = 0.f;
  if (i < 32) wshead[i] = 0u;
  if (i < SORT_CAP) sorted[i] = -1;
  if (blockIdx.x == 1027 && threadIdx.x < 64){
    unsigned short u = posu[2*threadIdx.x];
    int e = (u>>7)&0xFF;
    bool inr = (e >= 110 && e <= 140);
    unsigned long long m = __ballot(inr);
    if (threadIdx.x == 0) flag[0] = (__popcll(m) >= 32) ? 1u : 0u;
  }
}

__global__ void k_count(const int* __restrict__ sym, unsigned int* __restrict__ cnt){
  __shared__ unsigned int h[NSP];
  int t = threadIdx.x;
  if (t < NSP) h[t] = 0u;
  __syncthreads();
  int i = blockIdx.x*256 + t;
  atomicAdd(&h[sym[i]], 1u);
  __syncthreads();
  if (t < NSP) atomicAdd(&cnt[t], h[t]);
}

__global__ void k_starts(const unsigned int* __restrict__ cnt, int* __restrict__ starts){
  if (threadIdx.x == 0){
    int a = 0; starts[0] = 0;
    for (int s=0;s<NSP;s++){ a += (int)(((cnt[s]+63u)>>6)<<6); starts[s+1] = a; }
  }
}

__global__ void k_scatter(const int* __restrict__ sym, const int* __restrict__ starts,
                          unsigned int* __restrict__ cur, int* __restrict__ sorted){
  int i = blockIdx.x*256 + threadIdx.x;
  int s = sym[i];
  int lane = threadIdx.x & 63;
  #pragma unroll
  for (int ss=0; ss<NSP; ss++){
    unsigned long long m = __ballot(s==ss);
    if (s == ss){
      int leader = __builtin_ctzll(m);
      int cw = __popcll(m);
      unsigned int b = 0;
      if (lane == leader) b = atomicAdd(&cur[ss], (unsigned int)cw);
      b = (unsigned int)__shfl((int)b, leader);
      int rank = __popcll(m & ((1ull<<lane) - 1ull));
      sorted[starts[ss] + (int)b + rank] = i;
    }
  }
}

__global__ void k_prepw(const void* __restrict__ W1, const void* __restrict__ b1,
                        const void* __restrict__ W2, const unsigned int* __restrict__ flag,
                        unsigned short* __restrict__ w1t, unsigned short* __restrict__ w1p,
                        float* __restrict__ b1p, float* __restrict__ w2p){
  const int isbf = (int)flag[0];
  int idx = blockIdx.x*256 + threadIdx.x;   // covers 4*352*256 exactly
  int s = idx / (HP*NO);
  int r = idx % (HP*NO);
  int j = r / NO;
  int i = r % NO;
  float v = (j < HDIM) ? ldf(W1, (s*NO + i)*HDIM + j, isbf) : 0.f;
  unsigned short hv = f2bf(v);
  w1t[(s*HP + j)*NO + i] = hv;
  w1p[(s*NO + i)*HP + j] = hv;
  if (i == 0){
    b1p[s*HP + j] = (j < HDIM) ? ldf(b1, s*HDIM + j, isbf) : 0.f;
    w2p[s*HP + j] = (j < HDIM) ? ldf(W2, s*HDIM + j, isbf) : 0.f;
  }
}

// Fused per-tile kernel v4 (3 blocks/CU):
//  - two-pass GEMM1 (acc[3][4] twice) caps regs ~150 < 170 (512/3) -> no spill
//  - dpre held in 24 regs between passes; dpB OVERLAYS featB after both passes
//  - epilogue2 recomputes tanh (positions reloaded after GEMM2)
//  - Ecry atomics fused here (was k_seg)
// MFMA C/D layout (HW-verified r3 probe): reg q of lane l -> row=(l>>4)*4+q, col=l&15.
__global__ __launch_bounds__(256,3) void k_main(
    const int* __restrict__ sorted, const int* __restrict__ starts,
    const void* __restrict__ pos, const void* __restrict__ Wd,
    const unsigned short* __restrict__ W1T, const unsigned short* __restrict__ W1P,
    const float* __restrict__ b1p, const float* __restrict__ w2p,
    const void* __restrict__ b2g, const int* __restrict__ crys,
    const unsigned int* __restrict__ flag,
    float* __restrict__ Eatom, float* __restrict__ Ecry, float* __restrict__ forces)
{
  extern __shared__ char smem[];
  ushort4* wdT = (ushort4*)smem;            // [256] {wx,wy,wz,0}
  char* featB  = smem + 2048;               // bf16 [64][256], XOR-swz rows of 512B
  char* dpB    = smem + 2048;               // OVERLAY: bf16 [64] rows x 720B
  float* Fpart = (float*)(smem + 2048);     // OVERLAY after GEMM2: [4][64][3]
  float* Epart = (float*)(smem + 48128);    // [4][64]

  const int base = blockIdx.x*64;
  if (base >= starts[4]) return;
  const int isbf = (int)flag[0];
  int sp = 0;
  #pragma unroll
  for (int s=1;s<NSP;s++) sp = (base >= starts[s]) ? s : sp;

  const int tid = threadIdx.x;
  const int l = tid & 63;
  const int w = tid >> 6;
  const int c = l & 15;
  const int g = l >> 4;

  {
    float x = ldf(Wd, tid, isbf), y = ldf(Wd, NO+tid, isbf), z = ldf(Wd, 2*NO+tid, isbf);
    ushort4 u; u.x = f2bf(x); u.y = f2bf(y); u.z = f2bf(z); u.w = 0;
    wdT[tid] = u;
  }
  __syncthreads();

  // ---- phase 1: stage feat tile (row m=l, 64-col chunk w) ----
  {
    const int m = l;
    int a = sorted[base + m];
    float px=0.f, py=0.f, pz=0.f;
    if (a >= 0){ px = ldf(pos,3*a,isbf); py = ldf(pos,3*a+1,isbf); pz = ldf(pos,3*a+2,isbf); }
    const int swz = (m&7)<<4;
    char* rowp = featB + m*512;
    #pragma unroll
    for (int k8=0;k8<8;k8++){
      int i0 = w*64 + k8*8;
      unsigned int pk[4];
      #pragma unroll
      for (int p2=0;p2<4;p2++){
        unsigned short hv[2];
        #pragma unroll
        for (int e2=0;e2<2;e2++){
          ushort4 wv = wdT[i0 + 2*p2 + e2];
          float v = px*bf2f(wv.x) + py*bf2f(wv.y) + pz*bf2f(wv.z);
          float e = __expf(2.f*v);
          hv[e2] = f2bf(1.f - 2.f*rcpf(e+1.f));   // tanh via rcp
        }
        pk[p2] = (unsigned int)hv[0] | ((unsigned int)hv[1]<<16);
      }
      *(uint4*)(rowp + ((i0*2) ^ swz)) = make_uint4(pk[0],pk[1],pk[2],pk[3]);
    }
  }
  __syncthreads();

  // ---- phase 2: GEMM1 in TWO passes (acc[3][4] each); dpre kept in regs ----
  const unsigned short* W1Ts = W1T + sp*HP*NO;
  const float* b1s = b1p + sp*HP;
  const float* w2s = w2p + sp*HP;
  const int nT1 = (w==3) ? 4 : 6;   // frags per wave: 6,6,6,4
  float esp[4] = {0.f,0.f,0.f,0.f};
  uint2 dpk[2][3][4];               // [pass][t][nb] packed 4xbf16 dpre

  #pragma unroll
  for (int pass=0; pass<2; pass++){
    f32x4 acc[3][4];
    #pragma unroll
    for (int t=0;t<3;t++)
      #pragma unroll
      for (int nb=0;nb<4;nb++) acc[t][nb] = f32x4{0.f,0.f,0.f,0.f};

    #pragma unroll
    for (int kk=0; kk<8; kk++){
      short8 bfr[4];
      #pragma unroll
      for (int nb=0;nb<4;nb++){
        int m = nb*16 + c;
        bfr[nb] = *(const short8*)(featB + m*512 + ((kk*64 + g*16) ^ ((m&7)<<4)));
      }
      #pragma unroll
      for (int t=0;t<3;t++){
        int tt = pass*3 + t;
        if (tt < nT1){
          const short8 afr = *(const short8*)((const char*)W1Ts + ((6*w+tt)*16 + c)*512 + kk*64 + g*16);
          #pragma unroll
          for (int nb=0;nb<4;nb++)
            acc[t][nb] = __builtin_amdgcn_mfma_f32_16x16x32_bf16(afr, bfr[nb], acc[t][nb], 0,0,0);
        }
      }
    }
    // epilogue: silu + energy partial + dpre -> regs
    #pragma unroll
    for (int t=0;t<3;t++){
      int tt = pass*3 + t;
      if (tt < nT1){
        const int j0 = (6*w+tt)*16 + g*4;
        const float4 b1v = *(const float4*)(b1s + j0);
        const float4 w2v = *(const float4*)(w2s + j0);
        const float* b1a = (const float*)&b1v;
        const float* w2a = (const float*)&w2v;
        #pragma unroll
        for (int nb=0;nb<4;nb++){
          unsigned short dph[4];
          #pragma unroll
          for (int q=0;q<4;q++){
            float pre = acc[t][nb][q] + b1a[q];
            float sg = rcpf(1.f + __expf(-pre));     // sigmoid via rcp
            float h = pre*sg;
            esp[nb] += h*w2a[q];
            float dsl = sg*(1.f + pre*(1.f - sg));   // silu'
            dph[q] = f2bf(w2a[q]*dsl);               // dpre
          }
          dpk[pass][t][nb] = make_uint2((unsigned)dph[0] | ((unsigned)dph[1]<<16),
                                        (unsigned)dph[2] | ((unsigned)dph[3]<<16));
        }
      }
    }
  }
  #pragma unroll
  for (int nb=0;nb<4;nb++){
    float e = esp[nb];
    e += __shfl_xor(e, 16);
    e += __shfl_xor(e, 32);
    if (g == 0) Epart[w*64 + nb*16 + c] = e;
  }
  __syncthreads();   // all waves done reading featB -> overlay

  // ---- phase 3: write dpre regs -> dpB (linear, stride 720; max off 704) ----
  #pragma unroll
  for (int pass=0; pass<2; pass++){
    #pragma unroll
    for (int t=0;t<3;t++){
      int tt = pass*3 + t;
      if (tt < nT1){
        const int j0 = (6*w+tt)*16 + g*4;
        #pragma unroll
        for (int nb=0;nb<4;nb++){
          const int m = nb*16 + c;
          *(uint2*)(dpB + m*DP_STRIDE + j0*2) = dpk[pass][t][nb];
        }
      }
    }
  }
  __syncthreads();   // dpB complete

  // ---- phase 4: GEMM2 ----
  const unsigned short* W1Ps = W1P + sp*NO*HP;
  f32x4 acc2[4][4];
  #pragma unroll
  for (int t2=0;t2<4;t2++)
    #pragma unroll
    for (int nb=0;nb<4;nb++) acc2[t2][nb] = f32x4{0.f,0.f,0.f,0.f};

  #pragma unroll
  for (int kk=0; kk<11; kk++){
    short8 bfr[4];
    #pragma unroll
    for (int nb=0;nb<4;nb++){
      int m = nb*16 + c;
      bfr[nb] = *(const short8*)(dpB + m*DP_STRIDE + kk*64 + g*16);
    }
    #pragma unroll
    for (int t2=0;t2<4;t2++){
      const short8 afr = *(const short8*)((const char*)W1Ps + ((4*w+t2)*16 + c)*704 + kk*64 + g*16);
      #pragma unroll
      for (int nb=0;nb<4;nb++)
        acc2[t2][nb] = __builtin_amdgcn_mfma_f32_16x16x32_bf16(afr, bfr[nb], acc2[t2][nb], 0,0,0);
    }
  }

  // ---- phase 5: epilogue2 -- recompute f=tanh; dpos=(dfeat*(1-f^2))@Wd^T ----
  int a4[4]; float px4[4], py4[4], pz4[4];
  #pragma unroll
  for (int nb=0;nb<4;nb++){
    int aa = sorted[base + nb*16 + c];
    a4[nb] = aa;
    float x=0.f,y=0.f,z=0.f;
    if (aa >= 0){ x=ldf(pos,3*aa,isbf); y=ldf(pos,3*aa+1,isbf); z=ldf(pos,3*aa+2,isbf); }
    px4[nb]=x; py4[nb]=y; pz4[nb]=z;
  }
  float fax[4] = {0.f,0.f,0.f,0.f};
  float fay[4] = {0.f,0.f,0.f,0.f};
  float faz[4] = {0.f,0.f,0.f,0.f};
  #pragma unroll
  for (int t2=0;t2<4;t2++){
    const int i0 = (4*w+t2)*16 + g*4;
    #pragma unroll
    for (int q=0;q<4;q++){
      ushort4 wv = wdT[i0 + q];
      float wx = bf2f(wv.x), wy = bf2f(wv.y), wz = bf2f(wv.z);
      #pragma unroll
      for (int nb=0;nb<4;nb++){
        float v = px4[nb]*wx + py4[nb]*wy + pz4[nb]*wz;
        float e = __expf(2.f*v);
        float f = 1.f - 2.f*rcpf(e+1.f);
        float gsc = acc2[t2][nb][q] * (1.f - f*f);
        fax[nb] += gsc*wx;
        fay[nb] += gsc*wy;
        faz[nb] += gsc*wz;
      }
    }
  }
  #pragma unroll
  for (int nb=0;nb<4;nb++){
    float x = fax[nb], y = fay[nb], z = faz[nb];
    x += __shfl_xor(x, 16); x += __shfl_xor(x, 32);
    y += __shfl_xor(y, 16); y += __shfl_xor(y, 32);
    z += __shfl_xor(z, 16); z += __shfl_xor(z, 32);
    fax[nb] = x; fay[nb] = y; faz[nb] = z;
  }
  __syncthreads();   // all waves done reading dpB -> overlay Fpart
  #pragma unroll
  for (int nb=0;nb<4;nb++){
    if (g == 0){
      const int m = nb*16 + c;
      Fpart[w*192 + m*3 + 0] = fax[nb];
      Fpart[w*192 + m*3 + 1] = fay[nb];
      Fpart[w*192 + m*3 + 2] = faz[nb];
    }
  }
  __syncthreads();

  // ---- final: wave 0 sums partials; plain stores + fused Ecry atomic ----
  if (w == 0){
    int a = sorted[base + l];
    if (a >= 0){
      float E = Epart[l] + Epart[64+l] + Epart[128+l] + Epart[192+l]
              + ldf(b2g, sp, isbf);
      Eatom[a] = E;
      atomicAdd(&Ecry[crys[a]], E);   // fused segment-sum
      float fx = 0.f, fy = 0.f, fz = 0.f;
      #pragma unroll
      for (int ww=0; ww<4; ww++){
        fx += Fpart[ww*192 + l*3 + 0];
        fy += Fpart[ww*192 + l*3 + 1];
        fz += Fpart[ww*192 + l*3 + 2];
      }
      forces[3*a+0] = fx;
      forces[3*a+1] = fy;
      forces[3*a+2] = fz;
    }
  }
}

// Output: f32, reference order (energies=en[NTA], energy=E[NC], forces[NTA,3])
__global__ void k_out(const float* __restrict__ Eatom, const float* __restrict__ Ecry,
                      const float* __restrict__ Facc, float* __restrict__ out){
  int i = blockIdx.x*256 + threadIdx.x;   // grid covers 263168 exactly
  float v;
  if (i < NTA)            v = Eatom[i];
  else if (i < NTA + NC)  v = Ecry[i - NTA];
  else                    v = Facc[i - NTA - NC];
  out[i] = v;
}

extern "C" void kernel_launch(void* const* d_in, const int* in_sizes, int n_in,
                              void* d_out, int out_size, void* d_ws, size_t ws_size,
                              hipStream_t stream) {
  const int*   symbols    = (const int*)  d_in[0];
  const void*  positions  = d_in[1];
  // d_in[2] cells, d_in[3] pbcs, d_in[4] energyidx: unused by the math
  const int*   crystalidx = (const int*)  d_in[5];
  const void*  Wd         = d_in[6];
  const void*  W1         = d_in[7];
  const void*  b1         = d_in[8];
  const void*  W2         = d_in[9];
  const void*  b2         = d_in[10];
  float* dout = (float*)d_out;   // f32 output buffer

  char* ws = (char*)d_ws;
  unsigned int* cnt    = (unsigned int*)(ws + OFF_CNT);
  unsigned int* cur    = (unsigned int*)(ws + OFF_CUR);
  int*          starts = (int*)         (ws + OFF_START);
  unsigned int* flag   = (unsigned int*)(ws + OFF_FLAG);
  int*          sorted = (int*)         (ws + OFF_SORT);
  float*        b1p    = (float*)       (ws + OFF_B1P);
  float*        w2p    = (float*)       (ws + OFF_W2P);
  unsigned short* w1t  = (unsigned short*)(ws + OFF_W1T);
  unsigned short* w1pp = (unsigned short*)(ws + OFF_W1P);
  float*        Facc   = (float*)       (ws + OFF_FACC);   // forces[196608]
  float*        Eatom  = Facc + NTA*3;                     // [65536]
  float*        Ecry   = Eatom + NTA;                      // [1024]

  hipFuncSetAttribute((const void*)k_main,
                      hipFuncAttributeMaxDynamicSharedMemorySize, LDS_MAIN);

  k_init   <<<1028,256, 0, stream>>>(Facc, (unsigned int*)ws, sorted,
                                     (const unsigned short*)positions, flag);
  k_count  <<<256, 256, 0, stream>>>(symbols, cnt);
  k_starts <<<1,    64, 0, stream>>>(cnt, starts);
  k_scatter<<<256, 256, 0, stream>>>(symbols, starts, cur, sorted);
  k_prepw  <<<1408,256, 0, stream>>>(W1, b1, W2, flag, w1t, w1pp, b1p, w2p);
  k_main   <<<1028,256, LDS_MAIN, stream>>>(sorted, starts, positions, Wd,
                                            w1t, w1pp, b1p, w2p, b2, crystalidx,
                                            flag, Eatom, Ecry, Facc);
  k_out    <<<1028,256, 0, stream>>>(Eatom, Ecry, Facc, dout);
}

// Round 12
// 152.962 us; speedup vs baseline: 1.3790x; 1.0786x over previous
//
#include <hip/hip_runtime.h>

#define NTA 65536
#define NC 1024
#define NO 256
#define HDIM 332
#define HP 352          // H padded to multiple of 32
#define NSP 4
#define NOUT (NTA + NC + NTA*3)   // 263168 f32: en[NTA], E[NC], forces[NTA*3]
#define SORT_CAP (NTA + 4*128)    // 66048 (tiles padded to 128)

// LDS map for k_main (dynamic, 159744 B -> 1 block/CU, 8 waves):
//   [0,2048)          wdT    [256] ushort4
//   [2048,67584)      featB  bf16 [128] rows x 512B, XOR-swz
//   [67584,159744)    dpB    bf16 [128] rows x 720B, linear
//                     Epart  [8][128] f32      (OVERLAY dpB after GEMM2)
//                     Fpart  [8][128][3] f32   (OVERLAY dpB+4096)
#define DP_STRIDE 720
#define LDS_MAIN  159744

typedef __attribute__((ext_vector_type(8))) short short8;
typedef __attribute__((ext_vector_type(4))) float f32x4;

// ---- workspace offsets (bytes) ----
#define OFF_CNT   0
#define OFF_CUR   64
#define OFF_START 128        // 8 ints
#define OFF_FLAG  160        // 1 uint: 1 = float inputs are bf16, 0 = f32
#define OFF_SORT  256        // int[66048] -> ends 264448
#define OFF_B1P   264448     // f32[4*352] -> 270080
#define OFF_W2P   270080     // f32[4*352] -> 275712
#define OFF_W1T   275712     // bf16 [4][352][256] -> 996608
#define OFF_W1P   996608     // bf16 [4][256][352] -> 1717504
#define OFF_FACC  1717504    // f32: forces[196608], Eatom[65536], Ecry[1024]

__device__ __forceinline__ unsigned short f2bf(float f){
  unsigned int u = __builtin_bit_cast(unsigned int, f);
  u += 0x7fffu + ((u>>16)&1u);
  return (unsigned short)(u>>16);
}
__device__ __forceinline__ float bf2f(unsigned short h){
  unsigned int u = ((unsigned int)h)<<16;
  return __builtin_bit_cast(float, u);
}
__device__ __forceinline__ float ldf(const void* p, int idx, int isbf){
  if (isbf) return bf2f(((const unsigned short*)p)[idx]);
  return ((const float*)p)[idx];
}
__device__ __forceinline__ float rcpf(float x){ return __builtin_amdgcn_rcpf(x); }

__global__ void k_init(float* __restrict__ acc, unsigned int* __restrict__ wshead,
                       int* __restrict__ sorted, const unsigned short* __restrict__ posu,
                       unsigned int* __restrict__ flag){
  int i = blockIdx.x*256 + threadIdx.x;   // grid 1028*256 = 263168 exactly
  acc[i] = 0.f;
  if (i < 32) wshead[i] = 0u;
  if (i < SORT_CAP) sorted[i] = -1;
  if (blockIdx.x == 1027 && threadIdx.x < 64){
    unsigned short u = posu[2*threadIdx.x];
    int e = (u>>7)&0xFF;
    bool inr = (e >= 110 && e <= 140);
    unsigned long long m = __ballot(inr);
    if (threadIdx.x == 0) flag[0] = (__popcll(m) >= 32) ? 1u : 0u;
  }
}

__global__ void k_count(const int* __restrict__ sym, unsigned int* __restrict__ cnt){
  __shared__ unsigned int h[NSP];
  int t = threadIdx.x;
  if (t < NSP) h[t] = 0u;
  __syncthreads();
  int i = blockIdx.x*256 + t;
  atomicAdd(&h[sym[i]], 1u);
  __syncthreads();
  if (t < NSP) atomicAdd(&cnt[t], h[t]);
}

__global__ void k_starts(const unsigned int* __restrict__ cnt, int* __restrict__ starts){
  if (threadIdx.x == 0){
    int a = 0; starts[0] = 0;
    for (int s=0;s<NSP;s++){ a += (int)(((cnt[s]+127u)>>7)<<7); starts[s+1] = a; }
  }
}

__global__ void k_scatter(const int* __restrict__ sym, const int* __restrict__ starts,
                          unsigned int* __restrict__ cur, int* __restrict__ sorted){
  int i = blockIdx.x*256 + threadIdx.x;
  int s = sym[i];
  int lane = threadIdx.x & 63;
  #pragma unroll
  for (int ss=0; ss<NSP; ss++){
    unsigned long long m = __ballot(s==ss);
    if (s == ss){
      int leader = __builtin_ctzll(m);
      int cw = __popcll(m);
      unsigned int b = 0;
      if (lane == leader) b = atomicAdd(&cur[ss], (unsigned int)cw);
      b = (unsigned int)__shfl((int)b, leader);
      int rank = __popcll(m & ((1ull<<lane) - 1ull));
      sorted[starts[ss] + (int)b + rank] = i;
    }
  }
}

__global__ void k_prepw(const void* __restrict__ W1, const void* __restrict__ b1,
                        const void* __restrict__ W2, const unsigned int* __restrict__ flag,
                        unsigned short* __restrict__ w1t, unsigned short* __restrict__ w1p,
                        float* __restrict__ b1p, float* __restrict__ w2p){
  const int isbf = (int)flag[0];
  int idx = blockIdx.x*256 + threadIdx.x;   // covers 4*352*256 exactly
  int s = idx / (HP*NO);
  int r = idx % (HP*NO);
  int j = r / NO;
  int i = r % NO;
  float v = (j < HDIM) ? ldf(W1, (s*NO + i)*HDIM + j, isbf) : 0.f;
  unsigned short hv = f2bf(v);
  w1t[(s*HP + j)*NO + i] = hv;
  w1p[(s*NO + i)*HP + j] = hv;
  if (i == 0){
    b1p[s*HP + j] = (j < HDIM) ? ldf(b1, s*HDIM + j, isbf) : 0.f;
    w2p[s*HP + j] = (j < HDIM) ? ldf(W2, s*HDIM + j, isbf) : 0.f;
  }
}

// Fused per-tile kernel v5: 128-atom tile, 512 threads / 8 waves, 1 block/CU.
// Halves per-atom A-fragment traffic (8 MFMAs per A-frag) vs 64-atom tiles.
// GEMM1': pre^T[352][128] = W1T[352][256] x feat^T   (K=256, 8 k-steps)
//   waves 0-5: 3 j-frags each, waves 6-7: 2 (22 total). acc[3][8] = 96 regs.
// GEMM2': dfeat^T[256][128] = W1p[256][352] x dpre^T (K=352, 11 k-steps)
//   2 i-frags/wave. acc2[2][8] = 64 regs. No held-dpre (separate dpB) -> no spill.
// MFMA C/D layout (HW-verified r3 probe): reg q of lane l -> row=(l>>4)*4+q, col=l&15.
__global__ __launch_bounds__(512,2) void k_main(
    const int* __restrict__ sorted, const int* __restrict__ starts,
    const void* __restrict__ pos, const void* __restrict__ Wd,
    const unsigned short* __restrict__ W1T, const unsigned short* __restrict__ W1P,
    const float* __restrict__ b1p, const float* __restrict__ w2p,
    const void* __restrict__ b2g, const int* __restrict__ crys,
    const unsigned int* __restrict__ flag,
    float* __restrict__ Eatom, float* __restrict__ Ecry, float* __restrict__ forces)
{
  extern __shared__ char smem[];
  ushort4* wdT = (ushort4*)smem;               // [256]
  char* featB  = smem + 2048;                  // bf16 [128] rows x 512B, XOR-swz
  char* dpB    = smem + 2048 + 65536;          // bf16 [128] rows x 720B
  float* Epart = (float*)dpB;                  // overlay after GEMM2: [8][128]
  float* Fpart = (float*)(dpB + 4096);         // overlay: [8][128][3]

  const int base = blockIdx.x*128;
  if (base >= starts[4]) return;
  const int isbf = (int)flag[0];
  int sp = 0;
  #pragma unroll
  for (int s=1;s<NSP;s++) sp = (base >= starts[s]) ? s : sp;

  const int tid = threadIdx.x;
  const int l = tid & 63;
  const int w = tid >> 6;       // 0..7
  const int c = l & 15;
  const int g = l >> 4;

  if (tid < 256){
    float x = ldf(Wd, tid, isbf), y = ldf(Wd, NO+tid, isbf), z = ldf(Wd, 2*NO+tid, isbf);
    ushort4 u; u.x = f2bf(x); u.y = f2bf(y); u.z = f2bf(z); u.w = 0;
    wdT[tid] = u;
  }
  __syncthreads();

  // ---- phase 1: stage feat tile (row m=tid&127, 64-col quarter h=tid>>7) ----
  {
    const int m = tid & 127;
    const int h = tid >> 7;     // 0..3
    int a = sorted[base + m];
    float px=0.f, py=0.f, pz=0.f;
    if (a >= 0){ px = ldf(pos,3*a,isbf); py = ldf(pos,3*a+1,isbf); pz = ldf(pos,3*a+2,isbf); }
    const int swz = (m&7)<<4;
    char* rowp = featB + m*512;
    #pragma unroll
    for (int k8=0;k8<8;k8++){
      int i0 = h*64 + k8*8;
      unsigned int pk[4];
      #pragma unroll
      for (int p2=0;p2<4;p2++){
        unsigned short hv[2];
        #pragma unroll
        for (int e2=0;e2<2;e2++){
          ushort4 wv = wdT[i0 + 2*p2 + e2];
          float v = px*bf2f(wv.x) + py*bf2f(wv.y) + pz*bf2f(wv.z);
          float e = __expf(2.f*v);
          hv[e2] = f2bf(1.f - 2.f*rcpf(e+1.f));   // tanh via rcp
        }
        pk[p2] = (unsigned int)hv[0] | ((unsigned int)hv[1]<<16);
      }
      *(uint4*)(rowp + ((i0*2) ^ swz)) = make_uint4(pk[0],pk[1],pk[2],pk[3]);
    }
  }
  __syncthreads();

  // ---- phase 2: GEMM1 (j-frags: waves 0-5 x3, waves 6-7 x2) ----
  const unsigned short* W1Ts = W1T + sp*HP*NO;
  const int fr0 = (w<6) ? w*3 : 18 + (w-6)*2;
  const int nT  = (w<6) ? 3 : 2;
  f32x4 acc[3][8];
  #pragma unroll
  for (int t=0;t<3;t++)
    #pragma unroll
    for (int nb=0;nb<8;nb++) acc[t][nb] = f32x4{0.f,0.f,0.f,0.f};

  #pragma unroll
  for (int kk=0; kk<8; kk++){
    short8 bfr[8];
    #pragma unroll
    for (int nb=0;nb<8;nb++){
      int m = nb*16 + c;
      bfr[nb] = *(const short8*)(featB + m*512 + ((kk*64 + g*16) ^ ((m&7)<<4)));
    }
    #pragma unroll
    for (int t=0;t<3;t++){
      if (t < nT){
        const short8 afr = *(const short8*)((const char*)W1Ts + ((fr0+t)*16 + c)*512 + kk*64 + g*16);
        #pragma unroll
        for (int nb=0;nb<8;nb++)
          acc[t][nb] = __builtin_amdgcn_mfma_f32_16x16x32_bf16(afr, bfr[nb], acc[t][nb], 0,0,0);
      }
    }
  }

  // ---- epilogue 1: silu, E partials (regs), dpre -> dpB ----
  const float* b1s = b1p + sp*HP;
  const float* w2s = w2p + sp*HP;
  float esp[8] = {0.f,0.f,0.f,0.f,0.f,0.f,0.f,0.f};
  #pragma unroll
  for (int t=0;t<3;t++){
    if (t < nT){
      const int j0 = (fr0+t)*16 + g*4;
      const float4 b1v = *(const float4*)(b1s + j0);
      const float4 w2v = *(const float4*)(w2s + j0);
      const float* b1a = (const float*)&b1v;
      const float* w2a = (const float*)&w2v;
      #pragma unroll
      for (int nb=0;nb<8;nb++){
        const int m = nb*16 + c;
        unsigned short dph[4];
        #pragma unroll
        for (int q=0;q<4;q++){
          float pre = acc[t][nb][q] + b1a[q];
          float sg = rcpf(1.f + __expf(-pre));     // sigmoid via rcp
          float h = pre*sg;
          esp[nb] += h*w2a[q];
          float dsl = sg*(1.f + pre*(1.f - sg));   // silu'
          dph[q] = f2bf(w2a[q]*dsl);               // dpre
        }
        *(uint2*)(dpB + m*DP_STRIDE + j0*2) =
            make_uint2((unsigned)dph[0] | ((unsigned)dph[1]<<16),
                       (unsigned)dph[2] | ((unsigned)dph[3]<<16));
      }
    }
  }
  float e8[8];
  #pragma unroll
  for (int nb=0;nb<8;nb++){
    float e = esp[nb];
    e += __shfl_xor(e, 16);
    e += __shfl_xor(e, 32);
    e8[nb] = e;                 // valid at g==0
  }
  __syncthreads();   // dpB complete

  // ---- phase 3: GEMM2 (2 i-frags/wave) ----
  const unsigned short* W1Ps = W1P + sp*NO*HP;
  f32x4 acc2[2][8];
  #pragma unroll
  for (int t2=0;t2<2;t2++)
    #pragma unroll
    for (int nb=0;nb<8;nb++) acc2[t2][nb] = f32x4{0.f,0.f,0.f,0.f};

  #pragma unroll
  for (int kk=0; kk<11; kk++){
    short8 bfr[8];
    #pragma unroll
    for (int nb=0;nb<8;nb++){
      int m = nb*16 + c;
      bfr[nb] = *(const short8*)(dpB + m*DP_STRIDE + kk*64 + g*16);
    }
    #pragma unroll
    for (int t2=0;t2<2;t2++){
      const short8 afr = *(const short8*)((const char*)W1Ps + ((2*w+t2)*16 + c)*704 + kk*64 + g*16);
      #pragma unroll
      for (int nb=0;nb<8;nb++)
        acc2[t2][nb] = __builtin_amdgcn_mfma_f32_16x16x32_bf16(afr, bfr[nb], acc2[t2][nb], 0,0,0);
    }
  }

  // ---- epilogue 2: dpos = (dfeat * (1-feat^2)) @ Wd^T (featB still alive) ----
  float fax[8], fay[8], faz[8];
  #pragma unroll
  for (int nb=0;nb<8;nb++){ fax[nb]=0.f; fay[nb]=0.f; faz[nb]=0.f; }
  #pragma unroll
  for (int t2=0;t2<2;t2++){
    const int i0 = (2*w+t2)*16 + g*4;
    #pragma unroll
    for (int nb=0;nb<8;nb++){
      const int m = nb*16 + c;
      uint2 fpk = *(const uint2*)(featB + m*512 + ((i0*2) ^ ((m&7)<<4)));
      unsigned short fh[4];
      fh[0] = (unsigned short)(fpk.x & 0xffffu); fh[1] = (unsigned short)(fpk.x >> 16);
      fh[2] = (unsigned short)(fpk.y & 0xffffu); fh[3] = (unsigned short)(fpk.y >> 16);
      #pragma unroll
      for (int q=0;q<4;q++){
        float ff = bf2f(fh[q]);
        float gsc = acc2[t2][nb][q] * (1.f - ff*ff);
        ushort4 wv = wdT[i0 + q];
        fax[nb] += gsc*bf2f(wv.x);
        fay[nb] += gsc*bf2f(wv.y);
        faz[nb] += gsc*bf2f(wv.z);
      }
    }
  }
  #pragma unroll
  for (int nb=0;nb<8;nb++){
    float x = fax[nb], y = fay[nb], z = faz[nb];
    x += __shfl_xor(x, 16); x += __shfl_xor(x, 32);
    y += __shfl_xor(y, 16); y += __shfl_xor(y, 32);
    z += __shfl_xor(z, 16); z += __shfl_xor(z, 32);
    fax[nb] = x; fay[nb] = y; faz[nb] = z;
  }
  __syncthreads();   // all waves done with dpB -> overlay Epart/Fpart

  if (g == 0){
    #pragma unroll
    for (int nb=0;nb<8;nb++){
      const int m = nb*16 + c;
      Epart[w*128 + m] = e8[nb];
      Fpart[(w*128 + m)*3 + 0] = fax[nb];
      Fpart[(w*128 + m)*3 + 1] = fay[nb];
      Fpart[(w*128 + m)*3 + 2] = faz[nb];
    }
  }
  __syncthreads();

  // ---- final: first 128 threads sum 8 wave-partials, plain stores ----
  if (tid < 128){
    int a = sorted[base + tid];
    if (a >= 0){
      float E = ldf(b2g, sp, isbf);
      float fx = 0.f, fy = 0.f, fz = 0.f;
      #pragma unroll
      for (int ww=0; ww<8; ww++){
        E  += Epart[ww*128 + tid];
        fx += Fpart[(ww*128 + tid)*3 + 0];
        fy += Fpart[(ww*128 + tid)*3 + 1];
        fz += Fpart[(ww*128 + tid)*3 + 2];
      }
      Eatom[a] = E;
      atomicAdd(&Ecry[crys[a]], E);   // fused segment-sum
      forces[3*a+0] = fx;
      forces[3*a+1] = fy;
      forces[3*a+2] = fz;
    }
  }
}

// Output: f32, reference order (energies=en[NTA], energy=E[NC], forces[NTA,3])
__global__ void k_out(const float* __restrict__ Eatom, const float* __restrict__ Ecry,
                      const float* __restrict__ Facc, float* __restrict__ out){
  int i = blockIdx.x*256 + threadIdx.x;   // grid covers 263168 exactly
  float v;
  if (i < NTA)            v = Eatom[i];
  else if (i < NTA + NC)  v = Ecry[i - NTA];
  else                    v = Facc[i - NTA - NC];
  out[i] = v;
}

extern "C" void kernel_launch(void* const* d_in, const int* in_sizes, int n_in,
                              void* d_out, int out_size, void* d_ws, size_t ws_size,
                              hipStream_t stream) {
  const int*   symbols    = (const int*)  d_in[0];
  const void*  positions  = d_in[1];
  // d_in[2] cells, d_in[3] pbcs, d_in[4] energyidx: unused by the math
  const int*   crystalidx = (const int*)  d_in[5];
  const void*  Wd         = d_in[6];
  const void*  W1         = d_in[7];
  const void*  b1         = d_in[8];
  const void*  W2         = d_in[9];
  const void*  b2         = d_in[10];
  float* dout = (float*)d_out;   // f32 output buffer

  char* ws = (char*)d_ws;
  unsigned int* cnt    = (unsigned int*)(ws + OFF_CNT);
  unsigned int* cur    = (unsigned int*)(ws + OFF_CUR);
  int*          starts = (int*)         (ws + OFF_START);
  unsigned int* flag   = (unsigned int*)(ws + OFF_FLAG);
  int*          sorted = (int*)         (ws + OFF_SORT);
  float*        b1p    = (float*)       (ws + OFF_B1P);
  float*        w2p    = (float*)       (ws + OFF_W2P);
  unsigned short* w1t  = (unsigned short*)(ws + OFF_W1T);
  unsigned short* w1pp = (unsigned short*)(ws + OFF_W1P);
  float*        Facc   = (float*)       (ws + OFF_FACC);   // forces[196608]
  float*        Eatom  = Facc + NTA*3;                     // [65536]
  float*        Ecry   = Eatom + NTA;                      // [1024]

  hipFuncSetAttribute((const void*)k_main,
                      hipFuncAttributeMaxDynamicSharedMemorySize, LDS_MAIN);

  k_init   <<<1028,256, 0, stream>>>(Facc, (unsigned int*)ws, sorted,
                                     (const unsigned short*)positions, flag);
  k_count  <<<256, 256, 0, stream>>>(symbols, cnt);
  k_starts <<<1,    64, 0, stream>>>(cnt, starts);
  k_scatter<<<256, 256, 0, stream>>>(symbols, starts, cur, sorted);
  k_prepw  <<<1408,256, 0, stream>>>(W1, b1, W2, flag, w1t, w1pp, b1p, w2p);
  k_main   <<<516, 512, LDS_MAIN, stream>>>(sorted, starts, positions, Wd,
                                            w1t, w1pp, b1p, w2p, b2, crystalidx,
                                            flag, Eatom, Ecry, Facc);
  k_out    <<<1028,256, 0, stream>>>(Eatom, Ecry, Facc, dout);
}